// Round 1
// baseline (2482.927 us; speedup 1.0000x reference)
//
#include <hip/hip_runtime.h>

#define RDIM 256
#define NDIM 2048
#define CI 256
#define CH 64
#define NH 8
#define HC 512

typedef short bfrag __attribute__((ext_vector_type(8)));      // 8 bf16 (4 VGPR) MFMA operand
typedef float ffrag __attribute__((ext_vector_type(4)));      // 4 fp32 MFMA acc
typedef float f32x4 __attribute__((ext_vector_type(4)));
typedef unsigned short u16x4 __attribute__((ext_vector_type(4)));
typedef unsigned short u16x8 __attribute__((ext_vector_type(8)));

#define MFMA16 __builtin_amdgcn_mfma_f32_16x16x32_bf16

__device__ __forceinline__ unsigned short f2bf(float f) {
  union { float f; unsigned u; } v; v.f = f;
  unsigned r = v.u + 0x7fffu + ((v.u >> 16) & 1u);   // RNE
  return (unsigned short)(r >> 16);
}

// ---------------------------------------------------------------------------
// k0: pack weights into bf16 MFMA-frag order; zero pooling accumulators.
// Frag order: [(tile*KS + ks)*64 + lane]*8 + j, value = W^T[c = tile*16+(lane&15)]
//             [k = ks*32 + (lane>>4)*8 + j]  -> 16B/lane coalesced frag loads.
// ---------------------------------------------------------------------------
__global__ __launch_bounds__(256) void k0_prep(
    const float* __restrict__ Wk, const float* __restrict__ Wv,
    const float* __restrict__ Wg, const float* __restrict__ Wo,
    unsigned short* __restrict__ wkf, unsigned short* __restrict__ wvf,
    unsigned short* __restrict__ wgf, unsigned short* __restrict__ wof,
    float* __restrict__ qsum, float* __restrict__ msum) {
  const int tid = blockIdx.x * 256 + threadIdx.x;
  const int nth = gridDim.x * 256;
  for (int i = tid; i < RDIM * CI; i += nth) qsum[i] = 0.f;
  for (int i = tid; i < RDIM; i += nth) msum[i] = 0.f;
  for (int i = tid; i < 16384; i += nth) {           // Wk,Wv: [256][64], 4 tiles x 8 ks
    int j = i & 7, l = (i >> 3) & 63, ks = (i >> 9) & 7, ct = i >> 12;
    int k = ks * 32 + (l >> 4) * 8 + j, c = ct * 16 + (l & 15);
    wkf[i] = f2bf(Wk[k * 64 + c]);
    wvf[i] = f2bf(Wv[k * 64 + c]);
  }
  for (int i = tid; i < 131072; i += nth) {          // Wg: [256][512], 32 tiles x 8 ks
    int j = i & 7, l = (i >> 3) & 63, ks = (i >> 9) & 7, ct = i >> 12;
    int k = ks * 32 + (l >> 4) * 8 + j, c = ct * 16 + (l & 15);
    wgf[i] = f2bf(Wg[k * 512 + c]);
  }
  for (int i = tid; i < 131072; i += nth) {          // Wo: [512][256], 16 tiles x 16 ks
    int j = i & 7, l = (i >> 3) & 63, ks = (i >> 9) & 15, ct = i >> 13;
    int k = ks * 32 + (l >> 4) * 8 + j, co = ct * 16 + (l & 15);
    wof[i] = f2bf(Wo[k * 256 + co]);
  }
}

// ---------------------------------------------------------------------------
// k1: per (r, 128 n-rows): masked-mean partial pool (atomics) +
//     k = m@Wk  -> kbuf [R][N][64]   (mfma(WkT, m):  D[c][n], lane stores 4
//                                     consecutive c at fixed n -> 8B store)
//     v = m@Wv  -> vbuf [R][64][N]   (mfma(m, WvT):  D[n][c], lane stores 4
//                                     consecutive n at fixed c -> 8B store)
// m frag (8 consecutive c_in at row n=lane&15) serves as B for k and A for v.
// ---------------------------------------------------------------------------
__global__ __launch_bounds__(256) void k1_proj(
    const float* __restrict__ m, const float* __restrict__ mask,
    const unsigned short* __restrict__ wkf, const unsigned short* __restrict__ wvf,
    float* __restrict__ qsum, float* __restrict__ msum,
    unsigned short* __restrict__ kbuf, unsigned short* __restrict__ vbuf) {
  const int r = blockIdx.x >> 4;
  const int nb = (blockIdx.x & 15) << 7;
  const int t = threadIdx.x;
  const int lane = t & 63, w = t >> 6;
  __shared__ float msk[128];
  if (t < 128) msk[t] = mask[r * NDIM + nb + t];
  __syncthreads();
  {  // pooled-query partial sums: thread t owns channel c=t
    const float* mp = m + ((size_t)r * NDIM + nb) * CI + t;
    float s = 0.f;
#pragma unroll 8
    for (int i = 0; i < 128; ++i) s += mp[(size_t)i * CI] * msk[i];
    atomicAdd(&qsum[r * CI + t], s);
    if (t < 128) {
      float v = msk[t];
#pragma unroll
      for (int o = 32; o; o >>= 1) v += __shfl_down(v, o);
      if (lane == 0) atomicAdd(&msum[r], v);
    }
  }
  ffrag ak[4][2], av[4][2];
  const ffrag z = {0.f, 0.f, 0.f, 0.f};
#pragma unroll
  for (int ct = 0; ct < 4; ++ct)
#pragma unroll
    for (int st = 0; st < 2; ++st) { ak[ct][st] = z; av[ct][st] = z; }
  const int row0 = nb + w * 32;   // wave owns 2 n-subtiles (32 rows)
  const float* mbase = m + ((size_t)r * NDIM + row0 + (lane & 15)) * CI + (lane >> 4) * 8;
  for (int ks = 0; ks < 8; ++ks) {
    bfrag mf[2];
#pragma unroll
    for (int st = 0; st < 2; ++st) {
      const f32x4* p = (const f32x4*)(mbase + (size_t)st * 16 * CI + ks * 32);
      f32x4 x = p[0], y = p[1];
      bfrag q;
      q[0] = (short)f2bf(x[0]); q[1] = (short)f2bf(x[1]);
      q[2] = (short)f2bf(x[2]); q[3] = (short)f2bf(x[3]);
      q[4] = (short)f2bf(y[0]); q[5] = (short)f2bf(y[1]);
      q[6] = (short)f2bf(y[2]); q[7] = (short)f2bf(y[3]);
      mf[st] = q;
    }
#pragma unroll
    for (int ct = 0; ct < 4; ++ct) {
      bfrag wk = *(const bfrag*)(wkf + (((ct * 8 + ks) * 64 + lane) << 3));
      bfrag wv = *(const bfrag*)(wvf + (((ct * 8 + ks) * 64 + lane) << 3));
#pragma unroll
      for (int st = 0; st < 2; ++st) {
        ak[ct][st] = MFMA16(wk, mf[st], ak[ct][st], 0, 0, 0);  // D[c][n]
        av[ct][st] = MFMA16(mf[st], wv, av[ct][st], 0, 0, 0);  // D[n][c]
      }
    }
  }
#pragma unroll
  for (int ct = 0; ct < 4; ++ct)
#pragma unroll
    for (int st = 0; st < 2; ++st) {
      u16x4 pk, pv;
#pragma unroll
      for (int q = 0; q < 4; ++q) { pk[q] = f2bf(ak[ct][st][q]); pv[q] = f2bf(av[ct][st][q]); }
      int nk = row0 + st * 16 + (lane & 15);
      int ck = ct * 16 + (lane >> 4) * 4;
      *(u16x4*)(kbuf + ((size_t)r * NDIM + nk) * CH + ck) = pk;
      int nv = row0 + st * 16 + (lane >> 4) * 4;
      int cv = ct * 16 + (lane & 15);
      *(u16x4*)(vbuf + ((size_t)r * CH + cv) * NDIM + nv) = pv;
    }
}

// ---------------------------------------------------------------------------
// k2: per r: q = (qsum/msum)@Wq * 0.125; a = q.k^T + bias; softmax; o = p.v
// ---------------------------------------------------------------------------
__global__ __launch_bounds__(512) void k2_attn(
    const float* __restrict__ mask, const float* __restrict__ Wq,
    const float* __restrict__ qsum, const float* __restrict__ msum,
    const unsigned short* __restrict__ kbuf, const unsigned short* __restrict__ vbuf,
    float* __restrict__ ows) {
  const int r = blockIdx.x;
  const int t = threadIdx.x, lane = t & 63, w = t >> 6;
  __shared__ float qs[256];
  __shared__ float ql[16][64];          // rows 8..15 zero (M pad)
  __shared__ float al[8][2048];         // logits
  __shared__ unsigned short pl[16 * 2048];  // p bf16, XOR-swizzled rows
  __shared__ float rden[8];
  if (t < 256) qs[t] = qsum[r * CI + t];
  __syncthreads();
  const float inv = 1.f / (msum[r] + 1e-10f);
  {
    float s = 0.f;
    for (int ci = 0; ci < 256; ++ci) s += qs[ci] * Wq[ci * HC + t];
    ql[t >> 6][t & 63] = s * inv * 0.125f;   // 64^-0.5
    ql[8 + (t >> 6)][t & 63] = 0.f;
  }
  __syncthreads();
  bfrag qf[2];
#pragma unroll
  for (int kq = 0; kq < 2; ++kq)
#pragma unroll
    for (int j = 0; j < 8; ++j)
      qf[kq][j] = (short)f2bf(ql[lane & 15][kq * 32 + (lane >> 4) * 8 + j]);
  // phase a: QK^T, 16-n chunks
  for (int ch = w; ch < 128; ch += 8) {
    int n0 = ch << 4;
    ffrag d = {0.f, 0.f, 0.f, 0.f};
#pragma unroll
    for (int kq = 0; kq < 2; ++kq) {
      bfrag kf = *(const bfrag*)(kbuf + ((size_t)r * NDIM + n0 + (lane & 15)) * CH +
                                 kq * 32 + (lane >> 4) * 8);
      d = MFMA16(qf[kq], kf, d, 0, 0, 0);   // D[h][n]
    }
    float b = 1e9f * (mask[r * NDIM + n0 + (lane & 15)] - 1.f);
    if ((lane >> 4) < 2) {
#pragma unroll
      for (int q = 0; q < 4; ++q)
        al[(lane >> 4) * 4 + q][n0 + (lane & 15)] = d[q] + b;
    }
  }
  __syncthreads();
  {  // softmax: wave w owns head h=w
    const int h = w;
    float mx = -3.0e38f;
    for (int i = lane; i < 2048; i += 64) mx = fmaxf(mx, al[h][i]);
#pragma unroll
    for (int o = 32; o; o >>= 1) mx = fmaxf(mx, __shfl_xor(mx, o));
    float sum = 0.f;
    for (int i = lane; i < 2048; i += 64) {
      float e = __expf(al[h][i] - mx);
      sum += e;
      int byte = (h * 4096 + i * 2) ^ ((h & 7) << 4);
      *(unsigned short*)((char*)pl + byte) = f2bf(e);
    }
#pragma unroll
    for (int o = 32; o; o >>= 1) sum += __shfl_xor(sum, o);
    if (lane == 0) rden[h] = 1.f / sum;
    const int h2 = 8 + w;   // zero pad rows
    for (int i = lane; i < 2048; i += 64) {
      int byte = (h2 * 4096 + i * 2) ^ ((h2 & 7) << 4);
      *(unsigned short*)((char*)pl + byte) = 0;
    }
  }
  __syncthreads();
  // phase o: waves 0..3, c-tile = w
  if (w < 4) {
    ffrag acc = {0.f, 0.f, 0.f, 0.f};
    const int c0 = w << 4;
    for (int ks = 0; ks < 64; ++ks) {
      int hh = lane & 15;
      int byte = (hh * 4096 + (ks * 32 + (lane >> 4) * 8) * 2) ^ ((hh & 7) << 4);
      bfrag pf = *(const bfrag*)((char*)pl + byte);
      bfrag vf = *(const bfrag*)(vbuf + ((size_t)r * CH + c0 + (lane & 15)) * NDIM +
                                 ks * 32 + (lane >> 4) * 8);
      acc = MFMA16(pf, vf, acc, 0, 0, 0);   // D[h][c]
    }
    if ((lane >> 4) < 2) {
#pragma unroll
      for (int q = 0; q < 4; ++q) {
        int h = (lane >> 4) * 4 + q;
        ows[r * HC + h * CH + c0 + (lane & 15)] = acc[q] * rden[h];
      }
    }
  }
}

// ---------------------------------------------------------------------------
// k3: per (r, 128 n-rows): act = sigmoid(m@Wg + bg)*o ; out = act@Wo + bo
// m staged bf16 in swizzled LDS; act tile (64 rows/half) in swizzled LDS.
// ---------------------------------------------------------------------------
__global__ __launch_bounds__(512) void k3_out(
    const float* __restrict__ m, const unsigned short* __restrict__ wgf,
    const unsigned short* __restrict__ wof, const float* __restrict__ bg,
    const float* __restrict__ bo, const float* __restrict__ ows,
    float* __restrict__ out) {
  const int r = blockIdx.x >> 4;
  const int nb = (blockIdx.x & 15) << 7;
  const int t = threadIdx.x;
  const int lane = t & 63, w = t >> 6;
  __shared__ unsigned short ml[128 * 256];   // 64 KB, rows 512B, XOR swizzle
  __shared__ unsigned short actl[64 * 512];  // 64 KB, rows 1024B, XOR swizzle
  __shared__ float ogl[512], bgl[512], bol[256];
  ogl[t] = ows[r * HC + t];
  bgl[t] = bg[t];
  if (t < 256) bol[t] = bo[t];
  for (int ch = t; ch < 4096; ch += 512) {   // stage m -> bf16 LDS
    int n = ch >> 5;
    int c8 = (ch & 31) * 8;
    const f32x4* p = (const f32x4*)(m + ((size_t)r * NDIM + nb + n) * CI + c8);
    f32x4 x = p[0], y = p[1];
    u16x8 pk;
    pk[0] = f2bf(x[0]); pk[1] = f2bf(x[1]); pk[2] = f2bf(x[2]); pk[3] = f2bf(x[3]);
    pk[4] = f2bf(y[0]); pk[5] = f2bf(y[1]); pk[6] = f2bf(y[2]); pk[7] = f2bf(y[3]);
    int byte = (n * 512 + c8 * 2) ^ ((n & 7) << 4);
    *(u16x8*)((char*)ml + byte) = pk;
  }
  __syncthreads();
  const ffrag z = {0.f, 0.f, 0.f, 0.f};
  for (int half = 0; half < 2; ++half) {
    // GEMM1: glogit^T tiles, wave w -> hc-tiles w*4..w*4+3, n-tiles 0..3
    ffrag acc1[4][4];
#pragma unroll
    for (int a = 0; a < 4; ++a)
#pragma unroll
      for (int b = 0; b < 4; ++b) acc1[a][b] = z;
    for (int ks = 0; ks < 8; ++ks) {
      bfrag bf[4];
#pragma unroll
      for (int nt = 0; nt < 4; ++nt) {
        int n = half * 64 + nt * 16 + (lane & 15);
        int byte = (n * 512 + (ks * 32 + (lane >> 4) * 8) * 2) ^ ((n & 7) << 4);
        bf[nt] = *(const bfrag*)((char*)ml + byte);
      }
#pragma unroll
      for (int t4 = 0; t4 < 4; ++t4) {
        int ct = w * 4 + t4;
        bfrag a = *(const bfrag*)(wgf + (((ct * 8 + ks) * 64 + lane) << 3));
#pragma unroll
        for (int nt = 0; nt < 4; ++nt)
          acc1[t4][nt] = MFMA16(a, bf[nt], acc1[t4][nt], 0, 0, 0);  // D[hc][n]
      }
    }
    __syncthreads();   // previous half's GEMM2 reads of actl are done
#pragma unroll
    for (int t4 = 0; t4 < 4; ++t4)
#pragma unroll
      for (int nt = 0; nt < 4; ++nt) {
        int hc0 = (w * 4 + t4) * 16 + (lane >> 4) * 4;
        int n = nt * 16 + (lane & 15);
        u16x4 pk;
#pragma unroll
        for (int q = 0; q < 4; ++q) {
          float gl = acc1[t4][nt][q] + bgl[hc0 + q];
          float g = 1.f / (1.f + __expf(-gl));
          pk[q] = f2bf(g * ogl[hc0 + q]);
        }
        int byte = (n * 1024 + hc0 * 2) ^ ((n & 7) << 4);
        *(u16x4*)((char*)actl + byte) = pk;
      }
    __syncthreads();
    // GEMM2: out^T tiles, wave w -> co-tiles w*2, w*2+1, n-tiles 0..3
    ffrag acc2[2][4];
#pragma unroll
    for (int a = 0; a < 2; ++a)
#pragma unroll
      for (int b = 0; b < 4; ++b) acc2[a][b] = z;
    for (int ks = 0; ks < 16; ++ks) {
      bfrag bf[4];
#pragma unroll
      for (int nt = 0; nt < 4; ++nt) {
        int n = nt * 16 + (lane & 15);
        int byte = (n * 1024 + (ks * 32 + (lane >> 4) * 8) * 2) ^ ((n & 7) << 4);
        bf[nt] = *(const bfrag*)((char*)actl + byte);
      }
#pragma unroll
      for (int t2 = 0; t2 < 2; ++t2) {
        int ct = w * 2 + t2;
        bfrag a = *(const bfrag*)(wof + (((ct * 16 + ks) * 64 + lane) << 3));
#pragma unroll
        for (int nt = 0; nt < 4; ++nt)
          acc2[t2][nt] = MFMA16(a, bf[nt], acc2[t2][nt], 0, 0, 0);  // D[co][n]
      }
    }
#pragma unroll
    for (int t2 = 0; t2 < 2; ++t2)
#pragma unroll
      for (int nt = 0; nt < 4; ++nt) {
        int co0 = (w * 2 + t2) * 16 + (lane >> 4) * 4;
        int n = nb + half * 64 + nt * 16 + (lane & 15);
        f32x4 o;
#pragma unroll
        for (int q = 0; q < 4; ++q) o[q] = acc2[t2][nt][q] + bol[co0 + q];
        *(f32x4*)(out + ((size_t)r * NDIM + n) * CI + co0) = o;
      }
  }
}

// ---------------------------------------------------------------------------
extern "C" void kernel_launch(void* const* d_in, const int* in_sizes, int n_in,
                              void* d_out, int out_size, void* d_ws, size_t ws_size,
                              hipStream_t stream) {
  const float* m    = (const float*)d_in[0];
  const float* mask = (const float*)d_in[1];
  const float* Wq   = (const float*)d_in[2];
  const float* Wk   = (const float*)d_in[3];
  const float* Wv   = (const float*)d_in[4];
  const float* Wg   = (const float*)d_in[5];
  const float* bg   = (const float*)d_in[6];
  const float* Wo   = (const float*)d_in[7];
  const float* bo   = (const float*)d_in[8];
  float* out = (float*)d_out;
  char* ws = (char*)d_ws;
  // workspace layout (bytes)
  unsigned short* wkf  = (unsigned short*)(ws);                 //   32768
  unsigned short* wvf  = (unsigned short*)(ws + 32768);         //   32768
  unsigned short* wgf  = (unsigned short*)(ws + 65536);         //  262144
  unsigned short* wof  = (unsigned short*)(ws + 327680);        //  262144
  float*          qsum = (float*)(ws + 589824);                 //  262144
  float*          msum = (float*)(ws + 851968);                 //    1024
  float*          ows  = (float*)(ws + 852992);                 //  524288
  unsigned short* kbuf = (unsigned short*)(ws + 1377280);       // 67108864
  unsigned short* vbuf = (unsigned short*)(ws + 68486144);      // 67108864
  // total: 135595008 bytes (~129.3 MB)

  hipLaunchKernelGGL(k0_prep, dim3(256), dim3(256), 0, stream,
                     Wk, Wv, Wg, Wo, wkf, wvf, wgf, wof, qsum, msum);
  hipLaunchKernelGGL(k1_proj, dim3(4096), dim3(256), 0, stream,
                     m, mask, wkf, wvf, qsum, msum, kbuf, vbuf);
  hipLaunchKernelGGL(k2_attn, dim3(256), dim3(512), 0, stream,
                     mask, Wq, qsum, msum, kbuf, vbuf, ows);
  hipLaunchKernelGGL(k3_out, dim3(4096), dim3(512), 0, stream,
                     m, wgf, wof, bg, bo, ows, out);
}